// Round 5
// baseline (604.304 us; speedup 1.0000x reference)
//
#include <hip/hip_runtime.h>
#include <hip/hip_bf16.h>
#include <stdint.h>

// ---------------- problem constants (from setup_inputs) ----------------
constexpr int Mrows = 8192;   // B*S
constexpr int Hdim  = 2048;   // K of main GEMM
constexpr int Sdim  = 4096;
constexpr int HnD   = 4096;   // Hn*D
constexpr int Hn    = 32;
constexpr int Dd    = 128;
constexpr int Lc    = 16384;
constexpr int NFULL = 4352;   // 4096 q + 128 k + 32 w + 96 zero pad (34 tiles of 128)

typedef unsigned short u16;
typedef __attribute__((ext_vector_type(8))) short    bf16x8;
typedef __attribute__((ext_vector_type(4))) float    f32x4;
typedef __attribute__((ext_vector_type(8))) unsigned short u16x8;

__device__ __forceinline__ float bf2f(u16 u) {
    union { unsigned int i; float f; } v; v.i = ((unsigned int)u) << 16; return v.f;
}
__device__ __forceinline__ u16 f2bf(float f) {
    union { float f; unsigned int i; } v; v.f = f;
    unsigned int x = v.i;
    return (u16)((x + 0x7fffu + ((x >> 16) & 1u)) >> 16);   // RNE
}
__device__ __forceinline__ void gload_lds16(const void* g, void* l) {
    __builtin_amdgcn_global_load_lds(
        (const __attribute__((address_space(1))) void*)g,
        (__attribute__((address_space(3))) void*)l, 16, 0, 0);
}

// ------- 1) per-row stats: rms (RMSNorm), mu, rstd (LayerNorm) -------
__global__ __launch_bounds__(256) void stats_only(
    const float* __restrict__ x, float* __restrict__ rms,
    float* __restrict__ mu, float* __restrict__ rstd)
{
    int r = blockIdx.x, t = threadIdx.x;
    const float4* xr = (const float4*)(x + (size_t)r * Hdim);
    float4 a = xr[2 * t], bq = xr[2 * t + 1];
    float v[8] = {a.x, a.y, a.z, a.w, bq.x, bq.y, bq.z, bq.w};
    float s = 0.f, ss = 0.f;
    #pragma unroll
    for (int i = 0; i < 8; i++) { s += v[i]; ss += v[i] * v[i]; }
    for (int oo = 32; oo > 0; oo >>= 1) { s += __shfl_down(s, oo); ss += __shfl_down(ss, oo); }
    __shared__ float as[4], ass[4];
    if ((t & 63) == 0) { as[t >> 6] = s; ass[t >> 6] = ss; }
    __syncthreads();
    if (t == 0) {
        float S1 = as[0] + as[1] + as[2] + as[3];
        float S2 = ass[0] + ass[1] + ass[2] + ass[3];
        float mean = S1 / Hdim, msq = S2 / Hdim;
        rms[r]  = rsqrtf(msq + 1e-6f);
        mu[r]   = mean;
        rstd[r] = rsqrtf(msq - mean * mean + 1e-6f);
    }
}

// ---------------- 2) build B'^T = [c1*wqb | g*wk | wproj | 0]^T, [NFULL][H] ---
__global__ __launch_bounds__(256) void prep_wt(
    const float* __restrict__ wqb, const float* __restrict__ qn, const float* __restrict__ qns,
    const float* __restrict__ wk,  const float* __restrict__ g,  const float* __restrict__ wproj,
    u16* __restrict__ wt)
{
    __shared__ u16 tile[64][72];
    int k0 = blockIdx.x * 64, n0 = blockIdx.y * 64;
    int t = threadIdx.x;
    int lk = t >> 2, lc0 = (t & 3) * 16;
    int k = k0 + lk;
    float c1k = qn[k] * qns[k];
    float gk  = g[k];
    #pragma unroll
    for (int i = 0; i < 16; i++) {
        int n = n0 + lc0 + i;
        float val;
        if (n < 4096)      val = wqb[(size_t)k * HnD + n] * c1k;
        else if (n < 4224) val = wk[k * Dd + (n - 4096)] * gk;
        else if (n < 4256) val = wproj[k * Hn + (n - 4224)];
        else               val = 0.f;
        tile[lk][lc0 + i] = f2bf(val);
    }
    __syncthreads();
    int ln = t >> 2, lk0 = (t & 3) * 16;
    __align__(16) u16 o[16];
    #pragma unroll
    for (int i = 0; i < 16; i++) o[i] = tile[lk0 + i][ln];
    u16* dst = wt + (size_t)(n0 + ln) * Hdim + k0 + lk0;
    *(u16x8*)dst = *(const u16x8*)o;
    *(u16x8*)(dst + 8) = *((const u16x8*)o + 1);
}

// ---------------- 3) transpose hadamard matrices to bf16 (tiny) ----------
__global__ void transpose_h(const float* __restrict__ hq, const float* __restrict__ hk,
                            u16* __restrict__ hqt, u16* __restrict__ hkt)
{
    const float* src = blockIdx.x ? hk : hq;
    u16* dst = blockIdx.x ? hkt : hqt;
    int t = threadIdx.x;
    int n = t >> 1, kk0 = (t & 1) * 64;
    for (int i = 0; i < 64; i++) dst[n * Dd + kk0 + i] = f2bf(src[(kk0 + i) * Dd + n]);
}

// ---------------- 4) bdot[n]=sum_k b*wk, gdot[n]=sum_k g*wk ------------
__global__ __launch_bounds__(256) void bg_dot(
    const float* __restrict__ wk, const float* __restrict__ g, const float* __restrict__ b,
    float* __restrict__ bdot, float* __restrict__ gdot)
{
    int n = blockIdx.x, t = threadIdx.x;
    float sb = 0.f, sg = 0.f;
    for (int k = t; k < Hdim; k += 256) {
        float w = wk[k * Dd + n];
        sb += b[k] * w;
        sg += g[k] * w;
    }
    for (int o = 32; o > 0; o >>= 1) { sb += __shfl_down(sb, o); sg += __shfl_down(sg, o); }
    __shared__ float rb[4], rg[4];
    if ((t & 63) == 0) { rb[t >> 6] = sb; rg[t >> 6] = sg; }
    __syncthreads();
    if (t == 0) { bdot[n] = rb[0] + rb[1] + rb[2] + rb[3]; gdot[n] = rg[0] + rg[1] + rg[2] + rg[3]; }
}

// ---------------- 5) main fused GEMM: C = x @ B', epilogue by col range ----
// A: fp32 x [M][H], converted to bf16 in-kernel during staging.
// Bt [NFULL][H] bf16 (pre-scaled, transposed) via async global_load_lds.
// All outputs fp32.
__global__ __launch_bounds__(256) void main_gemm(
    const float* __restrict__ X, const u16* __restrict__ Bt,
    const float* __restrict__ rms, const float* __restrict__ mu, const float* __restrict__ rstd,
    const float* __restrict__ qbs,        // w_qb_scale [4096] fp32
    const float* __restrict__ bdot, const float* __restrict__ gdot,
    float* __restrict__ qpre,             // [M][4096] fp32 (d_out q region, pre-RoPE scratch)
    float* __restrict__ kpre,             // [M][128] fp32 ws
    float* __restrict__ wout)             // [M][32] fp32 weights output
{
    constexpr int BK = 32;
    __shared__ __align__(16) u16 smA[128 * BK];
    __shared__ __align__(16) u16 smB[128 * BK];
    int bm = blockIdx.x, bn = blockIdx.y;
    int tid = threadIdx.x, w = tid >> 6, lane = tid & 63;
    int quad = lane >> 4, l15 = lane & 15;
    int wrow = (w & 1) * 64, wcol = (w >> 1) * 64;

    f32x4 acc[4][4] = {};

    // B staging (async gload): per wave 32 rows, 16B per lane
    const int srow = w * 32 + (lane >> 2);   // +c*16
    const int kch  = (lane & 3) * 8;
    const u16* Bb = Bt + (size_t)(bn * 128) * Hdim;

    // A staging (manual cvt): each thread covers one row, 16 consecutive k
    const int arow  = tid >> 1;
    const int ahalf = (tid & 1) * 16;
    const float* Arow = X + (size_t)(bm * 128 + arow) * Hdim + ahalf;
    u16* sArow = smA + arow * BK + ahalf;

    for (int k0 = 0; k0 < Hdim; k0 += BK) {
        __syncthreads();
        #pragma unroll
        for (int c = 0; c < 2; c++) {
            int r = srow + c * 16;
            gload_lds16(Bb + (size_t)r * Hdim + k0 + kch, smB + (w * 32 + c * 16) * BK);
        }
        {
            float4 f0 = *(const float4*)(Arow + k0);
            float4 f1 = *(const float4*)(Arow + k0 + 4);
            float4 f2 = *(const float4*)(Arow + k0 + 8);
            float4 f3 = *(const float4*)(Arow + k0 + 12);
            __align__(16) u16 o[16] = {
                f2bf(f0.x), f2bf(f0.y), f2bf(f0.z), f2bf(f0.w),
                f2bf(f1.x), f2bf(f1.y), f2bf(f1.z), f2bf(f1.w),
                f2bf(f2.x), f2bf(f2.y), f2bf(f2.z), f2bf(f2.w),
                f2bf(f3.x), f2bf(f3.y), f2bf(f3.z), f2bf(f3.w)};
            *(u16x8*)sArow       = *(const u16x8*)o;
            *(u16x8*)(sArow + 8) = *((const u16x8*)o + 1);
        }
        __syncthreads();
        bf16x8 af[4], bfq[4];
        #pragma unroll
        for (int mt = 0; mt < 4; mt++)
            af[mt] = *(const bf16x8*)(smA + (wrow + mt * 16 + l15) * BK + quad * 8);
        #pragma unroll
        for (int nt = 0; nt < 4; nt++)
            bfq[nt] = *(const bf16x8*)(smB + (wcol + nt * 16 + l15) * BK + quad * 8);
        #pragma unroll
        for (int mt = 0; mt < 4; mt++)
            #pragma unroll
            for (int nt = 0; nt < 4; nt++)
                acc[mt][nt] = __builtin_amdgcn_mfma_f32_16x16x32_bf16(af[mt], bfq[nt], acc[mt][nt], 0, 0, 0);
    }

    // epilogue (fp32 stores)
    #pragma unroll
    for (int mt = 0; mt < 4; mt++) {
        int rbase = bm * 128 + wrow + mt * 16 + quad * 4;
        #pragma unroll
        for (int reg = 0; reg < 4; reg++) {
            int r = rbase + reg;
            if (bn < 32) {
                float sr = rms[r];
                #pragma unroll
                for (int nt = 0; nt < 4; nt++) {
                    int n = bn * 128 + wcol + nt * 16 + l15;
                    qpre[(size_t)r * HnD + n] = acc[mt][nt][reg] * sr * qbs[n];
                }
            } else if (bn == 32) {
                float sd = rstd[r], m_ = mu[r];
                #pragma unroll
                for (int nt = 0; nt < 4; nt++) {
                    int n = wcol + nt * 16 + l15;   // 0..127
                    kpre[(size_t)r * Dd + n] = acc[mt][nt][reg] * sd + bdot[n] - sd * m_ * gdot[n];
                }
            } else {
                #pragma unroll
                for (int nt = 0; nt < 4; nt++) {
                    int n = wcol + nt * 16 + l15;
                    if (n < Hn) wout[(size_t)r * Hn + n] = acc[mt][nt][reg];
                }
            }
        }
    }
}

// ---------------- 6) copy cache defaults into outputs (fp32) -------------
__global__ void copy_cache(const float* __restrict__ kc, const float* __restrict__ kcs,
                           float* __restrict__ dk, float* __restrict__ dks)
{
    int g = blockIdx.x * 256 + threadIdx.x;          // 262144 threads, 8 floats each
    ((float4*)dk)[2 * g]     = ((const float4*)kc)[2 * g];
    ((float4*)dk)[2 * g + 1] = ((const float4*)kc)[2 * g + 1];
    if (g < Lc / 8) {
        ((float4*)dks)[2 * g]     = ((const float4*)kcs)[2 * g];
        ((float4*)dks)[2 * g + 1] = ((const float4*)kcs)[2 * g + 1];
    }
}

// ---------------- 7) RoPE + Hadamard (MFMA) + quant (+scatter for K) ----
// src fp32 (q: qpre in d_out, in-place; k: kpre ws). Outputs fp32.
template <int IS_K>
__global__ __launch_bounds__(256) void post_kernel(
    const float* src,               // q: [M][4096]; k: [M][128] (fp32) — aliases dstq for q!
    const u16* __restrict__ ht,     // transposed hadamard [n][k] bf16
    const float* __restrict__ cosr, const float* __restrict__ sinr,  // [S][128] fp32
    const int* __restrict__ idx,    // k only
    float* dstq, float* __restrict__ dsts)
{
    constexpr int RP = 136;  // padded LDS row stride (elements)
    __shared__ __align__(16) u16 sA[32 * RP];
    __shared__ __align__(16) u16 sB[128 * RP];
    __shared__ float pamax[32][2];
    __shared__ int sidx[32];

    int blk = blockIdx.x, tid = threadIdx.x;

    { // stage hadamard^T into padded LDS
        int n = tid >> 1, kk0 = (tid & 1) * 64;
        const u16x8* gp = (const u16x8*)(ht + n * Dd + kk0);
        u16* lb = sB + n * RP + kk0;
        #pragma unroll
        for (int j = 0; j < 8; j++) *(u16x8*)(lb + j * 8) = gp[j];
    }
    { // stage 32 rows with RoPE applied (fp32 reads -> bf16 LDS)
        int r = tid >> 3, c = tid & 7;
        int d0 = c * 16;
        int s_ = IS_K ? ((blk * 32 + r) & (Sdim - 1)) : (blk & (Sdim - 1));
        const float* srow = src + (size_t)blk * 4096 + r * Dd;   // same addr law for q and k
        int p0 = (d0 + 64) & 127;
        float sign = (d0 < 64) ? -1.f : 1.f;
        float vv[16], pv[16], cv[16], sv[16];
        #pragma unroll
        for (int j = 0; j < 4; j++) {
            float4 a = *(const float4*)(srow + d0 + 4 * j);
            float4 p = *(const float4*)(srow + p0 + 4 * j);
            float4 cc = *(const float4*)(cosr + (size_t)s_ * Dd + d0 + 4 * j);
            float4 sc = *(const float4*)(sinr + (size_t)s_ * Dd + d0 + 4 * j);
            vv[4*j] = a.x; vv[4*j+1] = a.y; vv[4*j+2] = a.z; vv[4*j+3] = a.w;
            pv[4*j] = p.x; pv[4*j+1] = p.y; pv[4*j+2] = p.z; pv[4*j+3] = p.w;
            cv[4*j] = cc.x; cv[4*j+1] = cc.y; cv[4*j+2] = cc.z; cv[4*j+3] = cc.w;
            sv[4*j] = sc.x; sv[4*j+1] = sc.y; sv[4*j+2] = sc.z; sv[4*j+3] = sc.w;
        }
        __align__(16) u16 o[16];
        #pragma unroll
        for (int i = 0; i < 16; i++)
            o[i] = f2bf(vv[i] * cv[i] + sign * pv[i] * sv[i]);
        u16* la = sA + r * RP + d0;
        *(u16x8*)la = *(const u16x8*)o;
        *(u16x8*)(la + 8) = *((const u16x8*)o + 1);
        if (IS_K && tid < 32) sidx[tid] = idx[blk * 32 + tid];
    }
    __syncthreads();

    int w = tid >> 6, lane = tid & 63, quad = lane >> 4, l15 = lane & 15;
    int rs = (w & 1) * 16, cg = (w >> 1) * 64;
    f32x4 acc[4] = {};
    #pragma unroll
    for (int kb = 0; kb < 4; kb++) {
        bf16x8 a = *(const bf16x8*)(sA + (rs + l15) * RP + kb * 32 + quad * 8);
        #pragma unroll
        for (int nt = 0; nt < 4; nt++) {
            bf16x8 b = *(const bf16x8*)(sB + (cg + nt * 16 + l15) * RP + kb * 32 + quad * 8);
            acc[nt] = __builtin_amdgcn_mfma_f32_16x16x32_bf16(a, b, acc[nt], 0, 0, 0);
        }
    }
    // per-row partial absmax over this wave's 64 cols
    #pragma unroll
    for (int reg = 0; reg < 4; reg++) {
        float m = 0.f;
        #pragma unroll
        for (int nt = 0; nt < 4; nt++) m = fmaxf(m, fabsf(acc[nt][reg]));
        m = fmaxf(m, __shfl_xor(m, 8));
        m = fmaxf(m, __shfl_xor(m, 4));
        m = fmaxf(m, __shfl_xor(m, 2));
        m = fmaxf(m, __shfl_xor(m, 1));
        if (l15 == 0) pamax[rs + quad * 4 + reg][w >> 1] = m;
    }
    __syncthreads();
    #pragma unroll
    for (int reg = 0; reg < 4; reg++) {
        int r = rs + quad * 4 + reg;
        float am = fmaxf(pamax[r][0], pamax[r][1]);
        float scale = fmaxf(am * (1.f / 127.f), 1e-8f);
        float inv = 1.f / scale;
        size_t dro = IS_K ? (size_t)sidx[r] * Dd : (size_t)blk * 4096 + (size_t)r * Dd;
        #pragma unroll
        for (int nt = 0; nt < 4; nt++)
            dstq[dro + cg + nt * 16 + l15] = rintf(acc[nt][reg] * inv);
        if (l15 == 0 && (w >> 1) == 0)
            dsts[IS_K ? sidx[r] : blk * Hn + r] = scale;
    }
}

// ---------------- launch ------------------------------------------------
extern "C" void kernel_launch(void* const* d_in, const int* in_sizes, int n_in,
                              void* d_out, int out_size, void* d_ws, size_t ws_size,
                              hipStream_t stream) {
    (void)in_sizes; (void)n_in; (void)out_size; (void)ws_size;
    const float* x    = (const float*)d_in[0];
    const float* qn   = (const float*)d_in[1];
    const float* qns  = (const float*)d_in[2];
    const float* wqb  = (const float*)d_in[3];
    const float* wqbs = (const float*)d_in[4];
    const float* wk   = (const float*)d_in[5];
    const float* wpj  = (const float*)d_in[6];
    const float* g    = (const float*)d_in[7];
    const float* b    = (const float*)d_in[8];
    const float* cosr = (const float*)d_in[9];
    const float* sinr = (const float*)d_in[10];
    const float* hq   = (const float*)d_in[11];
    const float* hk   = (const float*)d_in[12];
    const float* kc   = (const float*)d_in[13];
    const float* kcs  = (const float*)d_in[14];
    const int*   idx  = (const int*)d_in[15];

    // ws layout — total ~22.2 MB
    char* ws = (char*)d_ws;
    size_t o = 0;
    u16* wt  = (u16*)(ws + o); o += (size_t)NFULL * Hdim * 2;   // 17.83 MB
    u16* hqt = (u16*)(ws + o); o += Dd * Dd * 2;
    u16* hkt = (u16*)(ws + o); o += Dd * Dd * 2;
    float* rmsb  = (float*)(ws + o); o += (size_t)Mrows * 4;
    float* mub   = (float*)(ws + o); o += (size_t)Mrows * 4;
    float* rstdb = (float*)(ws + o); o += (size_t)Mrows * 4;
    float* bdotb = (float*)(ws + o); o += 512;
    float* gdotb = (float*)(ws + o); o += 512;
    float* kpre  = (float*)(ws + o); o += (size_t)Mrows * Dd * 4;  // 4.19 MB

    float* out = (float*)d_out;
    float* oq  = out;                             // [M][4096]
    float* oqs = oq  + (size_t)Mrows * HnD;       // [M][32]
    float* ok  = oqs + (size_t)Mrows * Hn;        // [L][128]
    float* oks = ok  + (size_t)Lc * Dd;           // [L]
    float* ow  = oks + Lc;                        // [M][32]

    stats_only<<<Mrows, 256, 0, stream>>>(x, rmsb, mub, rstdb);
    prep_wt<<<dim3(Hdim / 64, NFULL / 64), 256, 0, stream>>>(wqb, qn, qns, wk, g, wpj, wt);
    transpose_h<<<2, 256, 0, stream>>>(hq, hk, hqt, hkt);
    bg_dot<<<Dd, 256, 0, stream>>>(wk, g, b, bdotb, gdotb);
    main_gemm<<<dim3(Mrows / 128, NFULL / 128), 256, 0, stream>>>(
        x, wt, rmsb, mub, rstdb, wqbs, bdotb, gdotb, oq, kpre, ow);
    copy_cache<<<(Lc * Dd / 8) / 256, 256, 0, stream>>>(kc, kcs, ok, oks);
    post_kernel<0><<<Mrows, 256, 0, stream>>>(oq, hqt, cosr, sinr, (const int*)nullptr, oq, oqs);
    post_kernel<1><<<Mrows / 32, 256, 0, stream>>>(kpre, hkt, cosr, sinr, idx, ok, oks);
}

// Round 6
// 578.288 us; speedup vs baseline: 1.0450x; 1.0450x over previous
//
#include <hip/hip_runtime.h>
#include <hip/hip_bf16.h>
#include <stdint.h>

// ---------------- problem constants (from setup_inputs) ----------------
constexpr int Mrows = 8192;   // B*S
constexpr int Hdim  = 2048;   // K of main GEMM
constexpr int Sdim  = 4096;
constexpr int HnD   = 4096;   // Hn*D
constexpr int Hn    = 32;
constexpr int Dd    = 128;
constexpr int Lc    = 16384;
constexpr int NFULL = 4352;   // 4096 q + 128 k + 32 w + 96 zero pad (34 tiles of 128)

typedef unsigned short u16;
typedef __attribute__((ext_vector_type(8))) short    bf16x8;
typedef __attribute__((ext_vector_type(4))) float    f32x4;
typedef __attribute__((ext_vector_type(8))) unsigned short u16x8;

__device__ __forceinline__ float bf2f(u16 u) {
    union { unsigned int i; float f; } v; v.i = ((unsigned int)u) << 16; return v.f;
}
__device__ __forceinline__ u16 f2bf(float f) {
    union { float f; unsigned int i; } v; v.f = f;
    unsigned int x = v.i;
    return (u16)((x + 0x7fffu + ((x >> 16) & 1u)) >> 16);   // RNE
}
__device__ __forceinline__ void gload_lds16(const void* g, void* l) {
    __builtin_amdgcn_global_load_lds(
        (const __attribute__((address_space(1))) void*)g,
        (__attribute__((address_space(3))) void*)l, 16, 0, 0);
}

// ------- 1) per-row stats (rms, mu, rstd) + fp32 -> bf16 copy of x -------
// xb prestaging kills the in-loop VALU cvt in main_gemm (R5: VALUBusy 47%).
__global__ __launch_bounds__(256) void stats_cvt(
    const float* __restrict__ x, u16* __restrict__ xb, float* __restrict__ rms,
    float* __restrict__ mu, float* __restrict__ rstd)
{
    int r = blockIdx.x, t = threadIdx.x;
    const float4* xr = (const float4*)(x + (size_t)r * Hdim);
    float4 a = xr[2 * t], bq = xr[2 * t + 1];
    float v[8] = {a.x, a.y, a.z, a.w, bq.x, bq.y, bq.z, bq.w};
    float s = 0.f, ss = 0.f;
    __align__(16) u16 o[8];
    #pragma unroll
    for (int i = 0; i < 8; i++) { s += v[i]; ss += v[i] * v[i]; o[i] = f2bf(v[i]); }
    ((u16x8*)(xb + (size_t)r * Hdim))[t] = *(const u16x8*)o;
    for (int oo = 32; oo > 0; oo >>= 1) { s += __shfl_down(s, oo); ss += __shfl_down(ss, oo); }
    __shared__ float as[4], ass[4];
    if ((t & 63) == 0) { as[t >> 6] = s; ass[t >> 6] = ss; }
    __syncthreads();
    if (t == 0) {
        float S1 = as[0] + as[1] + as[2] + as[3];
        float S2 = ass[0] + ass[1] + ass[2] + ass[3];
        float mean = S1 / Hdim, msq = S2 / Hdim;
        rms[r]  = rsqrtf(msq + 1e-6f);
        mu[r]   = mean;
        rstd[r] = rsqrtf(msq - mean * mean + 1e-6f);
    }
}

// ---------------- 2) build B'^T = [c1*wqb | g*wk | wproj | 0]^T, [NFULL][H] ---
__global__ __launch_bounds__(256) void prep_wt(
    const float* __restrict__ wqb, const float* __restrict__ qn, const float* __restrict__ qns,
    const float* __restrict__ wk,  const float* __restrict__ g,  const float* __restrict__ wproj,
    u16* __restrict__ wt)
{
    __shared__ u16 tile[64][72];
    int k0 = blockIdx.x * 64, n0 = blockIdx.y * 64;
    int t = threadIdx.x;
    int lk = t >> 2, lc0 = (t & 3) * 16;
    int k = k0 + lk;
    float c1k = qn[k] * qns[k];
    float gk  = g[k];
    #pragma unroll
    for (int i = 0; i < 16; i++) {
        int n = n0 + lc0 + i;
        float val;
        if (n < 4096)      val = wqb[(size_t)k * HnD + n] * c1k;
        else if (n < 4224) val = wk[k * Dd + (n - 4096)] * gk;
        else if (n < 4256) val = wproj[k * Hn + (n - 4224)];
        else               val = 0.f;
        tile[lk][lc0 + i] = f2bf(val);
    }
    __syncthreads();
    int ln = t >> 2, lk0 = (t & 3) * 16;
    __align__(16) u16 o[16];
    #pragma unroll
    for (int i = 0; i < 16; i++) o[i] = tile[lk0 + i][ln];
    u16* dst = wt + (size_t)(n0 + ln) * Hdim + k0 + lk0;
    *(u16x8*)dst = *(const u16x8*)o;
    *(u16x8*)(dst + 8) = *((const u16x8*)o + 1);
}

// ------- 3) transpose hadamard matrices to bf16 (LDS-tiled, coalesced) ----
__global__ __launch_bounds__(256) void transpose_h(
    const float* __restrict__ hq, const float* __restrict__ hk,
    u16* __restrict__ hqt, u16* __restrict__ hkt)
{
    __shared__ float tile[128][129];
    const float* src = blockIdx.x ? hk : hq;
    u16* dst = blockIdx.x ? hkt : hqt;
    int t = threadIdx.x;
    int r = t >> 1, h = (t & 1) * 64;
    #pragma unroll
    for (int j = 0; j < 16; j++) {
        float4 v = *(const float4*)(src + r * Dd + h + 4 * j);
        tile[r][h + 4 * j]     = v.x;
        tile[r][h + 4 * j + 1] = v.y;
        tile[r][h + 4 * j + 2] = v.z;
        tile[r][h + 4 * j + 3] = v.w;
    }
    __syncthreads();
    #pragma unroll
    for (int j0 = 0; j0 < 64; j0 += 8) {
        __align__(16) u16 o[8];
        #pragma unroll
        for (int j = 0; j < 8; j++) o[j] = f2bf(tile[h + j0 + j][r]);
        *(u16x8*)(dst + r * Dd + h + j0) = *(const u16x8*)o;
    }
}

// ---------------- 4) bdot[n]=sum_k b*wk, gdot[n]=sum_k g*wk ------------
__global__ __launch_bounds__(256) void bg_dot(
    const float* __restrict__ wk, const float* __restrict__ g, const float* __restrict__ b,
    float* __restrict__ bdot, float* __restrict__ gdot)
{
    int n = blockIdx.x, t = threadIdx.x;
    float sb = 0.f, sg = 0.f;
    for (int k = t; k < Hdim; k += 256) {
        float w = wk[k * Dd + n];
        sb += b[k] * w;
        sg += g[k] * w;
    }
    for (int o = 32; o > 0; o >>= 1) { sb += __shfl_down(sb, o); sg += __shfl_down(sg, o); }
    __shared__ float rb[4], rg[4];
    if ((t & 63) == 0) { rb[t >> 6] = sb; rg[t >> 6] = sg; }
    __syncthreads();
    if (t == 0) { bdot[n] = rb[0] + rb[1] + rb[2] + rb[3]; gdot[n] = rg[0] + rg[1] + rg[2] + rg[3]; }
}

// ---------------- 5) main fused GEMM: C = xb @ B', epilogue by col range ----
// A [M][H] bf16 (prestaged xb), Bt [NFULL][H] bf16 — both via global_load_lds.
__global__ __launch_bounds__(256) void main_gemm(
    const u16* __restrict__ A, const u16* __restrict__ Bt,
    const float* __restrict__ rms, const float* __restrict__ mu, const float* __restrict__ rstd,
    const float* __restrict__ qbs,        // w_qb_scale [4096] fp32
    const float* __restrict__ bdot, const float* __restrict__ gdot,
    float* __restrict__ qpre,             // [M][4096] fp32 (d_out q region, pre-RoPE scratch)
    float* __restrict__ kpre,             // [M][128] fp32 ws
    float* __restrict__ wout)             // [M][32] fp32 weights output
{
    constexpr int BK = 32;
    __shared__ __align__(16) u16 smA[128 * BK];
    __shared__ __align__(16) u16 smB[128 * BK];
    int bm = blockIdx.x, bn = blockIdx.y;
    int tid = threadIdx.x, w = tid >> 6, lane = tid & 63;
    int quad = lane >> 4, l15 = lane & 15;
    int wrow = (w & 1) * 64, wcol = (w >> 1) * 64;

    f32x4 acc[4][4] = {};

    // staging: per wave 32 rows of A and 32 of B, 16B per lane
    const int srow = w * 32 + (lane >> 2);   // +c*16
    const int kch  = (lane & 3) * 8;
    const u16* Ab = A  + (size_t)(bm * 128) * Hdim;
    const u16* Bb = Bt + (size_t)(bn * 128) * Hdim;

    for (int k0 = 0; k0 < Hdim; k0 += BK) {
        __syncthreads();
        #pragma unroll
        for (int c = 0; c < 2; c++) {
            int r = srow + c * 16;
            gload_lds16(Ab + (size_t)r * Hdim + k0 + kch, smA + (w * 32 + c * 16) * BK);
            gload_lds16(Bb + (size_t)r * Hdim + k0 + kch, smB + (w * 32 + c * 16) * BK);
        }
        __syncthreads();
        bf16x8 af[4], bfq[4];
        #pragma unroll
        for (int mt = 0; mt < 4; mt++)
            af[mt] = *(const bf16x8*)(smA + (wrow + mt * 16 + l15) * BK + quad * 8);
        #pragma unroll
        for (int nt = 0; nt < 4; nt++)
            bfq[nt] = *(const bf16x8*)(smB + (wcol + nt * 16 + l15) * BK + quad * 8);
        #pragma unroll
        for (int mt = 0; mt < 4; mt++)
            #pragma unroll
            for (int nt = 0; nt < 4; nt++)
                acc[mt][nt] = __builtin_amdgcn_mfma_f32_16x16x32_bf16(af[mt], bfq[nt], acc[mt][nt], 0, 0, 0);
    }

    // epilogue (fp32 stores)
    #pragma unroll
    for (int mt = 0; mt < 4; mt++) {
        int rbase = bm * 128 + wrow + mt * 16 + quad * 4;
        #pragma unroll
        for (int reg = 0; reg < 4; reg++) {
            int r = rbase + reg;
            if (bn < 32) {
                float sr = rms[r];
                #pragma unroll
                for (int nt = 0; nt < 4; nt++) {
                    int n = bn * 128 + wcol + nt * 16 + l15;
                    qpre[(size_t)r * HnD + n] = acc[mt][nt][reg] * sr * qbs[n];
                }
            } else if (bn == 32) {
                float sd = rstd[r], m_ = mu[r];
                #pragma unroll
                for (int nt = 0; nt < 4; nt++) {
                    int n = wcol + nt * 16 + l15;   // 0..127
                    kpre[(size_t)r * Dd + n] = acc[mt][nt][reg] * sd + bdot[n] - sd * m_ * gdot[n];
                }
            } else {
                #pragma unroll
                for (int nt = 0; nt < 4; nt++) {
                    int n = wcol + nt * 16 + l15;
                    if (n < Hn) wout[(size_t)r * Hn + n] = acc[mt][nt][reg];
                }
            }
        }
    }
}

// ---------------- 6) copy cache defaults into outputs (fp32) -------------
__global__ void copy_cache(const float* __restrict__ kc, const float* __restrict__ kcs,
                           float* __restrict__ dk, float* __restrict__ dks)
{
    int g = blockIdx.x * 256 + threadIdx.x;          // 262144 threads, 8 floats each
    ((float4*)dk)[2 * g]     = ((const float4*)kc)[2 * g];
    ((float4*)dk)[2 * g + 1] = ((const float4*)kc)[2 * g + 1];
    if (g < Lc / 8) {
        ((float4*)dks)[2 * g]     = ((const float4*)kcs)[2 * g];
        ((float4*)dks)[2 * g + 1] = ((const float4*)kcs)[2 * g + 1];
    }
}

// ---------------- 7) RoPE + Hadamard (MFMA) + quant (+scatter for K) ----
// src fp32 (q: qpre in d_out, in-place; k: kpre ws). Outputs fp32.
template <int IS_K>
__global__ __launch_bounds__(256) void post_kernel(
    const float* src,               // q: [M][4096]; k: [M][128] (fp32) — aliases dstq for q!
    const u16* __restrict__ ht,     // transposed hadamard [n][k] bf16
    const float* __restrict__ cosr, const float* __restrict__ sinr,  // [S][128] fp32
    const int* __restrict__ idx,    // k only
    float* dstq, float* __restrict__ dsts)
{
    constexpr int RP = 136;  // padded LDS row stride (elements)
    __shared__ __align__(16) u16 sA[32 * RP];
    __shared__ __align__(16) u16 sB[128 * RP];
    __shared__ float pamax[32][2];
    __shared__ int sidx[32];

    int blk = blockIdx.x, tid = threadIdx.x;

    { // stage hadamard^T into padded LDS
        int n = tid >> 1, kk0 = (tid & 1) * 64;
        const u16x8* gp = (const u16x8*)(ht + n * Dd + kk0);
        u16* lb = sB + n * RP + kk0;
        #pragma unroll
        for (int j = 0; j < 8; j++) *(u16x8*)(lb + j * 8) = gp[j];
    }
    { // stage 32 rows with RoPE applied (fp32 reads -> bf16 LDS)
        int r = tid >> 3, c = tid & 7;
        int d0 = c * 16;
        int s_ = IS_K ? ((blk * 32 + r) & (Sdim - 1)) : (blk & (Sdim - 1));
        const float* srow = src + (size_t)blk * 4096 + r * Dd;   // same addr law for q and k
        int p0 = (d0 + 64) & 127;
        float sign = (d0 < 64) ? -1.f : 1.f;
        float vv[16], pv[16], cv[16], sv[16];
        #pragma unroll
        for (int j = 0; j < 4; j++) {
            float4 a = *(const float4*)(srow + d0 + 4 * j);
            float4 p = *(const float4*)(srow + p0 + 4 * j);
            float4 cc = *(const float4*)(cosr + (size_t)s_ * Dd + d0 + 4 * j);
            float4 sc = *(const float4*)(sinr + (size_t)s_ * Dd + d0 + 4 * j);
            vv[4*j] = a.x; vv[4*j+1] = a.y; vv[4*j+2] = a.z; vv[4*j+3] = a.w;
            pv[4*j] = p.x; pv[4*j+1] = p.y; pv[4*j+2] = p.z; pv[4*j+3] = p.w;
            cv[4*j] = cc.x; cv[4*j+1] = cc.y; cv[4*j+2] = cc.z; cv[4*j+3] = cc.w;
            sv[4*j] = sc.x; sv[4*j+1] = sc.y; sv[4*j+2] = sc.z; sv[4*j+3] = sc.w;
        }
        __align__(16) u16 o[16];
        #pragma unroll
        for (int i = 0; i < 16; i++)
            o[i] = f2bf(vv[i] * cv[i] + sign * pv[i] * sv[i]);
        u16* la = sA + r * RP + d0;
        *(u16x8*)la = *(const u16x8*)o;
        *(u16x8*)(la + 8) = *((const u16x8*)o + 1);
        if (IS_K && tid < 32) sidx[tid] = idx[blk * 32 + tid];
    }
    __syncthreads();

    int w = tid >> 6, lane = tid & 63, quad = lane >> 4, l15 = lane & 15;
    int rs = (w & 1) * 16, cg = (w >> 1) * 64;
    f32x4 acc[4] = {};
    #pragma unroll
    for (int kb = 0; kb < 4; kb++) {
        bf16x8 a = *(const bf16x8*)(sA + (rs + l15) * RP + kb * 32 + quad * 8);
        #pragma unroll
        for (int nt = 0; nt < 4; nt++) {
            bf16x8 b = *(const bf16x8*)(sB + (cg + nt * 16 + l15) * RP + kb * 32 + quad * 8);
            acc[nt] = __builtin_amdgcn_mfma_f32_16x16x32_bf16(a, b, acc[nt], 0, 0, 0);
        }
    }
    // per-row partial absmax over this wave's 64 cols
    #pragma unroll
    for (int reg = 0; reg < 4; reg++) {
        float m = 0.f;
        #pragma unroll
        for (int nt = 0; nt < 4; nt++) m = fmaxf(m, fabsf(acc[nt][reg]));
        m = fmaxf(m, __shfl_xor(m, 8));
        m = fmaxf(m, __shfl_xor(m, 4));
        m = fmaxf(m, __shfl_xor(m, 2));
        m = fmaxf(m, __shfl_xor(m, 1));
        if (l15 == 0) pamax[rs + quad * 4 + reg][w >> 1] = m;
    }
    __syncthreads();
    #pragma unroll
    for (int reg = 0; reg < 4; reg++) {
        int r = rs + quad * 4 + reg;
        float am = fmaxf(pamax[r][0], pamax[r][1]);
        float scale = fmaxf(am * (1.f / 127.f), 1e-8f);
        float inv = 1.f / scale;
        size_t dro = IS_K ? (size_t)sidx[r] * Dd : (size_t)blk * 4096 + (size_t)r * Dd;
        #pragma unroll
        for (int nt = 0; nt < 4; nt++)
            dstq[dro + cg + nt * 16 + l15] = rintf(acc[nt][reg] * inv);
        if (l15 == 0 && (w >> 1) == 0)
            dsts[IS_K ? sidx[r] : blk * Hn + r] = scale;
    }
}

// ---------------- launch ------------------------------------------------
extern "C" void kernel_launch(void* const* d_in, const int* in_sizes, int n_in,
                              void* d_out, int out_size, void* d_ws, size_t ws_size,
                              hipStream_t stream) {
    (void)in_sizes; (void)n_in; (void)out_size; (void)ws_size;
    const float* x    = (const float*)d_in[0];
    const float* qn   = (const float*)d_in[1];
    const float* qns  = (const float*)d_in[2];
    const float* wqb  = (const float*)d_in[3];
    const float* wqbs = (const float*)d_in[4];
    const float* wk   = (const float*)d_in[5];
    const float* wpj  = (const float*)d_in[6];
    const float* g    = (const float*)d_in[7];
    const float* b    = (const float*)d_in[8];
    const float* cosr = (const float*)d_in[9];
    const float* sinr = (const float*)d_in[10];
    const float* hq   = (const float*)d_in[11];
    const float* hk   = (const float*)d_in[12];
    const float* kc   = (const float*)d_in[13];
    const float* kcs  = (const float*)d_in[14];
    const int*   idx  = (const int*)d_in[15];

    // ws layout — total ~55.8 MB (53.7 MB proven safe in R3: deterministic run)
    char* ws = (char*)d_ws;
    size_t o = 0;
    u16* xb  = (u16*)(ws + o); o += (size_t)Mrows * Hdim * 2;   // 33.55 MB
    u16* wt  = (u16*)(ws + o); o += (size_t)NFULL * Hdim * 2;   // 17.83 MB
    u16* hqt = (u16*)(ws + o); o += Dd * Dd * 2;
    u16* hkt = (u16*)(ws + o); o += Dd * Dd * 2;
    float* rmsb  = (float*)(ws + o); o += (size_t)Mrows * 4;
    float* mub   = (float*)(ws + o); o += (size_t)Mrows * 4;
    float* rstdb = (float*)(ws + o); o += (size_t)Mrows * 4;
    float* bdotb = (float*)(ws + o); o += 512;
    float* gdotb = (float*)(ws + o); o += 512;
    float* kpre  = (float*)(ws + o); o += (size_t)Mrows * Dd * 4;  // 4.19 MB

    float* out = (float*)d_out;
    float* oq  = out;                             // [M][4096]
    float* oqs = oq  + (size_t)Mrows * HnD;       // [M][32]
    float* ok  = oqs + (size_t)Mrows * Hn;        // [L][128]
    float* oks = ok  + (size_t)Lc * Dd;           // [L]
    float* ow  = oks + Lc;                        // [M][32]

    stats_cvt<<<Mrows, 256, 0, stream>>>(x, xb, rmsb, mub, rstdb);
    prep_wt<<<dim3(Hdim / 64, NFULL / 64), 256, 0, stream>>>(wqb, qn, qns, wk, g, wpj, wt);
    transpose_h<<<2, 256, 0, stream>>>(hq, hk, hqt, hkt);
    bg_dot<<<Dd, 256, 0, stream>>>(wk, g, b, bdotb, gdotb);
    main_gemm<<<dim3(Mrows / 128, NFULL / 128), 256, 0, stream>>>(
        xb, wt, rmsb, mub, rstdb, wqbs, bdotb, gdotb, oq, kpre, ow);
    copy_cache<<<(Lc * Dd / 8) / 256, 256, 0, stream>>>(kc, kcs, ok, oks);
    post_kernel<0><<<Mrows, 256, 0, stream>>>(oq, hqt, cosr, sinr, (const int*)nullptr, oq, oqs);
    post_kernel<1><<<Mrows / 32, 256, 0, stream>>>(kpre, hkt, cosr, sinr, idx, ok, oks);
}